// Round 5
// baseline (207.207 us; speedup 1.0000x reference)
//
#include <hip/hip_runtime.h>
#include <hip/hip_bf16.h>

typedef __attribute__((ext_vector_type(8))) short short8;
typedef __attribute__((ext_vector_type(4))) short short4v;
typedef __attribute__((ext_vector_type(4))) float f32x4;
typedef __attribute__((ext_vector_type(16))) float f32x16;

#define B_  2
#define S_  2048
#define H_  16
#define HD_ 64
#define D_  1024
#define QSCALE 0.18033688f   /* 0.125 * log2(e): folds softmax exp2 conversion into Q proj */

__device__ __forceinline__ short f2bs(float f) {
  union { float f; unsigned u; } c; c.f = f;
  unsigned u = c.u;
  u += 0x7fffu + ((u >> 16) & 1u);   // RNE; inputs are never NaN
  return (short)(u >> 16);
}

__device__ __forceinline__ unsigned pack_bf16(float a, float b) {
  __hip_bfloat162 h = __float22bfloat162_rn(float2{a, b});   // v_cvt_pk_bf16_f32
  return *reinterpret_cast<unsigned*>(&h);
}

__device__ __forceinline__ float fexp2(float x) {
#if __has_builtin(__builtin_amdgcn_exp2f)
  return __builtin_amdgcn_exp2f(x);
#else
  return exp2f(x);
#endif
}

__device__ __forceinline__ float frcp(float x) {
#if __has_builtin(__builtin_amdgcn_rcpf)
  return __builtin_amdgcn_rcpf(x);
#else
  return 1.0f / x;
#endif
}

#define GL2LDS(gp, lp) __builtin_amdgcn_global_load_lds( \
    (const __attribute__((address_space(1))) unsigned int*)(gp), \
    (__attribute__((address_space(3))) unsigned int*)(lp), 16, 0, 0)

// ---------------- fused prep: x/y convert + all three weight transposes ----------------
__global__ __launch_bounds__(256)
void prep_kernel(const float* __restrict__ x, const float* __restrict__ y,
                 short* __restrict__ xb, short* __restrict__ yb,
                 const float* __restrict__ Wkv, short* __restrict__ Wkvt,
                 const float* __restrict__ Wq, short* __restrict__ Wqt,
                 const float* __restrict__ Wo, short* __restrict__ Wot) {
  __shared__ float tile[64][65];
  int bx = blockIdx.x;
  if (bx < 8192) {                      // convert x (1M float4) then y (1M float4)
    int i = bx * 256 + threadIdx.x;
    const float4* src; short4v* dst; int j;
    if (i < (1 << 20)) { src = (const float4*)x; dst = (short4v*)xb; j = i; }
    else               { src = (const float4*)y; dst = (short4v*)yb; j = i - (1 << 20); }
    float4 f = src[j];
    short4v o;
    o.x = f2bs(f.x); o.y = f2bs(f.y); o.z = f2bs(f.z); o.w = f2bs(f.w);
    dst[j] = o;
    return;
  }
  bx -= 8192;
  const float* in; short* out; int C, c0, r0;
  if (bx < 512)      { in = Wkv; out = Wkvt; C = 2048; c0 = (bx & 31) * 64; r0 = (bx >> 5) * 64; }
  else if (bx < 768) { bx -= 512; in = Wq; out = Wqt; C = 1024; c0 = (bx & 15) * 64; r0 = (bx >> 4) * 64; }
  else               { bx -= 768; in = Wo; out = Wot; C = 1024; c0 = (bx & 15) * 64; r0 = (bx >> 4) * 64; }
  const int tx = threadIdx.x & 63, ty = threadIdx.x >> 6;
#pragma unroll
  for (int i = 0; i < 16; ++i) {
    int r = ty + i * 4;
    tile[r][tx] = in[(size_t)(r0 + r) * C + c0 + tx];
  }
  __syncthreads();
#pragma unroll
  for (int i = 0; i < 16; ++i) {
    int r = ty + i * 4;
    out[(size_t)(c0 + r) * 1024 + r0 + tx] = f2bs(tile[tx][r]);
  }
}

// ---------------- GEMM body: C[128,128] tile of A[M,K] @ Bt[N,K]^T + bias ----------------
// Double-buffered LDS (As0|As1|Bs0|Bs1, 8KB each), BK=32, ONE barrier per K-step.
// MODE 1's Vt output is stored with the s-dim PERMUTED within 16-blocks (dword order
// [0,1,4,5,2,3,6,7] per 8-dword block) so attn's PV A-fragment is the straight pack of
// each lane's own softmax registers (no cross-lane redistribution needed).
template <int MODE>
__device__ __forceinline__ void gemm_body(const short* __restrict__ A, const short* __restrict__ Bt,
                                          const float* __restrict__ bias,
                                          void* __restrict__ out0, void* __restrict__ out1,
                                          int m0, int n0, int K, short* smem) {
  short* As_ = smem;            // 2 x 4096 shorts
  short* Bs_ = smem + 8192;     // 2 x 4096 shorts
  const int tid = threadIdx.x;
  const int w = tid >> 6, lane = tid & 63;
  const int q15 = lane & 15, quad = lane >> 4;
  const int wm = (w >> 1) * 64, wn = (w & 1) * 64;

  f32x4 acc[4][4];
#pragma unroll
  for (int i = 0; i < 4; ++i)
#pragma unroll
    for (int j = 0; j < 4; ++j) acc[i][j] = f32x4{0.f, 0.f, 0.f, 0.f};

  const int srow = w * 16 + (lane >> 2);                    // row 0..63 (first half)
  const int gch  = (lane & 3) ^ ((lane >> 3) & 3);          // swizzled global chunk
  const short* Ag = A + (size_t)(m0 + srow) * K + gch * 8;
  const short* Bg = Bt + (size_t)(n0 + srow) * K + gch * 8;
  const int lof = srow * 32 + (lane & 3) * 8;

  // prologue: stage K-tile 0 into buffer 0
  GL2LDS(Ag,                  As_ + lof);
  GL2LDS(Ag + (size_t)64 * K, As_ + lof + 2048);
  GL2LDS(Bg,                  Bs_ + lof);
  GL2LDS(Bg + (size_t)64 * K, Bs_ + lof + 2048);

  const int NT = K >> 5;
  for (int kt = 0; kt < NT; ++kt) {
    __syncthreads();                      // cur buf DMA done; prev reads of next buf drained
    const short* Ac = As_ + (kt & 1) * 4096;
    const short* Bc = Bs_ + (kt & 1) * 4096;
    if (kt + 1 < NT) {                    // issue next tile into the idle buffer
      const short* a2 = Ag + (size_t)(kt + 1) * 32;
      const short* b2 = Bg + (size_t)(kt + 1) * 32;
      short* ad = As_ + ((kt & 1) ^ 1) * 4096 + lof;
      short* bd = Bs_ + ((kt & 1) ^ 1) * 4096 + lof;
      GL2LDS(a2,                  ad);
      GL2LDS(a2 + (size_t)64 * K, ad + 2048);
      GL2LDS(b2,                  bd);
      GL2LDS(b2 + (size_t)64 * K, bd + 2048);
    }
    short8 af[4], bf[4];
#pragma unroll
    for (int mi = 0; mi < 4; ++mi) {
      int rr = wm + mi * 16 + q15;
      af[mi] = *(const short8*)(Ac + rr * 32 + ((quad ^ ((rr >> 1) & 3)) * 8));
    }
#pragma unroll
    for (int ni = 0; ni < 4; ++ni) {
      int rr = wn + ni * 16 + q15;
      bf[ni] = *(const short8*)(Bc + rr * 32 + ((quad ^ ((rr >> 1) & 3)) * 8));
    }
#pragma unroll
    for (int mi = 0; mi < 4; ++mi)
#pragma unroll
      for (int ni = 0; ni < 4; ++ni)
        acc[mi][ni] = __builtin_amdgcn_mfma_f32_16x16x32_bf16(af[mi], bf[ni], acc[mi][ni], 0, 0, 0);
  }
  __syncthreads();                        // protect smem (VT transpose region) reuse below

  if constexpr (MODE == 0) {
#pragma unroll
    for (int mi = 0; mi < 4; ++mi)
#pragma unroll
      for (int ni = 0; ni < 4; ++ni) {
        const int n = n0 + wn + ni * 16 + q15;
        const float bn = bias[n];
#pragma unroll
        for (int r = 0; r < 4; ++r) {
          const int m = m0 + wm + mi * 16 + quad * 4 + r;
          int b = m >> 11, s = m & 2047, hh = n >> 6, d = n & 63;
          ((short*)out0)[((size_t)((b * H_ + hh) * S_ + s) << 6) + d] = f2bs((acc[mi][ni][r] + bn) * QSCALE);
        }
      }
  } else {
    const int hh = n0 >> 7;
    const int bb = m0 >> 11;
    const size_t bh = (size_t)(bb * H_ + hh);
    const int s0 = m0 & 2047;
    if ((w & 1) == 0) {
#pragma unroll
      for (int mi = 0; mi < 4; ++mi)
#pragma unroll
        for (int ni = 0; ni < 4; ++ni) {
          const float bn = bias[n0 + ni * 16 + q15];
#pragma unroll
          for (int r = 0; r < 4; ++r) {
            const int s = s0 + wm + mi * 16 + quad * 4 + r;
            ((short*)out0)[((bh * S_ + s) << 6) + ni * 16 + q15] = f2bs(acc[mi][ni][r] + bn);
          }
        }
    } else {
      short* VT = smem;
#pragma unroll
      for (int mi = 0; mi < 4; ++mi)
#pragma unroll
        for (int ni = 0; ni < 4; ++ni) {
          const int d = ni * 16 + q15;
          const float bn = bias[n0 + 64 + ni * 16 + q15];
#pragma unroll
          for (int t = 0; t < 2; ++t) {
            const int chunk = (wm >> 1) + mi * 8 + quad * 2 + t;
            unsigned pk = pack_bf16(acc[mi][ni][2 * t] + bn, acc[mi][ni][2 * t + 1] + bn);
            *reinterpret_cast<unsigned*>(VT + d * 128 + ((chunk ^ (d & 15)) * 2)) = pk;
          }
        }
    }
    __syncthreads();
    {
      short* VT = smem;
      const int d = tid >> 2, t4 = tid & 3;
      unsigned vals[16];
#pragma unroll
      for (int c = 0; c < 16; ++c) {
        int chunk = t4 * 16 + c;
        vals[c] = *reinterpret_cast<unsigned*>(VT + d * 128 + ((chunk ^ (d & 15)) * 2));
      }
      uint4* dst = (uint4*)((short*)out1 + ((bh * HD_ + d) << 11) + s0 + t4 * 32);
      // s-permuted store: per 8-dword block, stored order [0,1,4,5,2,3,6,7] so that
      // stored position 16t+8h+j holds s = 16t + (j&3) + 8*(j>>2) + 4h (attn PV pairing).
      dst[0] = uint4{vals[0], vals[1], vals[4],  vals[5]};
      dst[1] = uint4{vals[2], vals[3], vals[6],  vals[7]};
      dst[2] = uint4{vals[8], vals[9], vals[12], vals[13]};
      dst[3] = uint4{vals[10], vals[11], vals[14], vals[15]};
    }
  }
}

// fused stage-1: logical blocks [0,512) -> KV proj, [512,768) -> Q proj.
// XCD-chunked remap (768 % 8 == 0, bijective).
__global__ __launch_bounds__(256)
void proj_kernel(const short* __restrict__ xb, const short* __restrict__ Wkvt,
                 const float* __restrict__ bkv, short* __restrict__ Kb, short* __restrict__ Vtb,
                 const short* __restrict__ yb, const short* __restrict__ Wqt,
                 const float* __restrict__ bq, short* __restrict__ Qb) {
  __shared__ __align__(16) short smem[16384];
  int bx = blockIdx.x;
  bx = (bx & 7) * 96 + (bx >> 3);
  if (bx < 512)
    gemm_body<1>(xb, Wkvt, bkv, Kb, Vtb, (bx >> 4) * 128, (bx & 15) * 128, 1024, smem);
  else {
    bx -= 512;
    gemm_body<0>(yb, Wqt, bq, Qb, nullptr, (bx >> 3) * 128, (bx & 7) * 128, 1024, smem);
  }
}

// ---------------- O projection: 64x64 tile, BK=64, double-buffered, 1 barrier/iter ----------------
__global__ __launch_bounds__(256)
void gemm_o_kernel(const short* __restrict__ A, const short* __restrict__ Bt,
                   const float* __restrict__ bias, float* __restrict__ out) {
  __shared__ __align__(16) short lds[16384];    // A0|A1|B0|B1, 4096 shorts each
  const int tid = threadIdx.x;
  const int w = tid >> 6, lane = tid & 63;
  const int q15 = lane & 15, quad = lane >> 4;
  const int m0 = blockIdx.y * 64, n0 = blockIdx.x * 64;
  const int wm = (w >> 1) * 32, wn = (w & 1) * 32;
  const int xw = q15 & 7;

  f32x4 acc[2][2];
#pragma unroll
  for (int i = 0; i < 2; ++i)
#pragma unroll
    for (int j = 0; j < 2; ++j) acc[i][j] = f32x4{0.f, 0.f, 0.f, 0.f};

  const int srow = w * 8 + (lane >> 3);          // 0..31
  const int gch  = (lane & 7) ^ (srow & 7);
  const int loff = w * 512 + lane * 8;
  const short* Ag = A + (size_t)(m0 + srow) * 1024 + gch * 8;
  const short* Bg = Bt + (size_t)(n0 + srow) * 1024 + gch * 8;

  GL2LDS(Ag,             lds + loff);
  GL2LDS(Ag + 32 * 1024, lds + loff + 2048);
  GL2LDS(Bg,             lds + 8192 + loff);
  GL2LDS(Bg + 32 * 1024, lds + 8192 + loff + 2048);

  for (int kt = 0; kt < 16; ++kt) {
    __syncthreads();                            // cur buf DMA done; prev reads drained
    const short* Ac = lds + ((kt & 1) ? 4096 : 0);
    const short* Bc = lds + 8192 + ((kt & 1) ? 4096 : 0);
    if (kt < 15) {
      const short* a2 = Ag + (kt + 1) * 64;
      const short* b2 = Bg + (kt + 1) * 64;
      short* ad = lds + ((kt & 1) ? 0 : 4096) + loff;
      short* bd = lds + 8192 + ((kt & 1) ? 0 : 4096) + loff;
      GL2LDS(a2,             ad);
      GL2LDS(a2 + 32 * 1024, ad + 2048);
      GL2LDS(b2,             bd);
      GL2LDS(b2 + 32 * 1024, bd + 2048);
    }
    short8 af[2][2], bf[2][2];
#pragma unroll
    for (int mi = 0; mi < 2; ++mi)
#pragma unroll
      for (int kk = 0; kk < 2; ++kk)
        af[mi][kk] = *(const short8*)(Ac + (wm + mi * 16 + q15) * 64 + (((kk * 4 + quad) ^ xw) * 8));
#pragma unroll
    for (int ni = 0; ni < 2; ++ni)
#pragma unroll
      for (int kk = 0; kk < 2; ++kk)
        bf[ni][kk] = *(const short8*)(Bc + (wn + ni * 16 + q15) * 64 + (((kk * 4 + quad) ^ xw) * 8));
#pragma unroll
    for (int mi = 0; mi < 2; ++mi)
#pragma unroll
      for (int ni = 0; ni < 2; ++ni)
#pragma unroll
        for (int kk = 0; kk < 2; ++kk)
          acc[mi][ni] = __builtin_amdgcn_mfma_f32_16x16x32_bf16(af[mi][kk], bf[ni][kk], acc[mi][ni], 0, 0, 0);
  }

#pragma unroll
  for (int mi = 0; mi < 2; ++mi)
#pragma unroll
    for (int ni = 0; ni < 2; ++ni) {
      const int n = n0 + wn + ni * 16 + q15;
      const float bn = bias[n];
#pragma unroll
      for (int r = 0; r < 4; ++r) {
        const int m = m0 + wm + mi * 16 + quad * 4 + r;
        out[(size_t)m * 1024 + n] = acc[mi][ni][r] + bn;
      }
    }
}

// ---------------- flash attention: 32x32x16 MFMA, fully in-register P, 3 blocks/CU ----------
// grid 512 (XCD-swizzled: 4 (b,h) pairs per XCD x 16 q-tiles). 256 threads = 4 waves; q-tile
// 128 rows; wave owns 32 q-rows (q = lane&31). LDS 48KB -> 3 blocks/CU = 12 waves/CU for
// latency hiding (was 8). Swapped QK^T; softmax lane-local; PV A-fragment = straight pack of
// own exp values against the proj-time s-permuted V (verified round 4). No P LDS.
// Q pre-scaled by 0.125*log2e (scores in log2 domain, no-max exact softmax).
// LDS layout (shorts): Ks0[4096] Ks1[4096] Vs0[4096] Vs1[4096] Q[8192] = 49152 B.
__global__ __launch_bounds__(256, 3)
void attn_kernel(const short* __restrict__ Q, const short* __restrict__ K,
                 const short* __restrict__ Vt, short* __restrict__ Out) {
  __shared__ __align__(16) short lds[24576];
  short* QP = lds + 16384;
  const int tid = threadIdx.x;
  const int w = tid >> 6, lane = tid & 63;     // w in 0..3
  const int l31 = lane & 31, h5 = lane >> 5;
  const int rsw = l31 & 7;                     // row-XOR swizzle (rows == l31 mod 8 everywhere)
  const int bx = blockIdx.x;
  const int xcd = bx & 7, slot = bx >> 3;      // slot 0..63
  const int pp = xcd * 4 + (slot >> 4);        // (b,h) pair: 4 per XCD
  const int qt = slot & 15;                    // 16 q-tiles of 128 rows
  const int h = pp & 15, b = pp >> 4;
  const size_t bh = (size_t)(b * H_ + h);
  const short* Qg = Q + bh * (S_ * HD_) + qt * (128 * HD_);
  const short* Kg = K + bh * (S_ * HD_);
  const short* Vg = Vt + bh * (HD_ * S_);

  const int srow = tid >> 3;                   // 0..31
  const int gch  = (tid & 7) ^ (srow & 7);
  const int loff = tid * 8;                    // shorts, 0..2047

  // stage Q (128 rows, 4 rounds of 32 rows) + K/V tile 0 into buf 0
  {
    const short* qg = Qg + srow * 64 + gch * 8;
#pragma unroll
    for (int t = 0; t < 4; ++t) GL2LDS(qg + t * 2048, QP + loff + t * 2048);
  }
  const short* kg = Kg + srow * 64 + gch * 8;
  const short* vg = Vg + (size_t)srow * S_ + gch * 8;
  GL2LDS(kg,                   lds + loff);
  GL2LDS(kg + 2048,            lds + loff + 2048);
  GL2LDS(vg,                   lds + 8192 + loff);
  GL2LDS(vg + (size_t)32 * S_, lds + 8192 + loff + 2048);
  __syncthreads();

  // Q B-fragment: col q = l31 (tile row w*32+l31), k = d = kk*16 + h5*8 + j
  short8 aq[4];
#pragma unroll
  for (int kk = 0; kk < 4; ++kk)
    aq[kk] = *(const short8*)(QP + (w * 32 + l31) * 64 + (((kk * 2 + h5) ^ rsw) * 8));

  f32x16 oacc[2];
#pragma unroll
  for (int i = 0; i < 16; ++i) { oacc[0][i] = 0.f; oacc[1][i] = 0.f; }
  float lsum = 0.f;
  f32x16 z16;
#pragma unroll
  for (int i = 0; i < 16; ++i) z16[i] = 0.f;

  for (int kt = 0; kt < 32; ++kt) {
    __syncthreads();                           // cur buf ready; everyone done with next buf
    const short* Kc = lds + ((kt & 1) ? 4096 : 0);
    const short* Vc = lds + 8192 + ((kt & 1) ? 4096 : 0);
    if (kt < 31) {                             // DMA next tile into the idle buffer
      const short* k2 = kg + (kt + 1) * 4096;
      const short* v2 = vg + (kt + 1) * 64;
      short* kd = lds + ((kt & 1) ? 0 : 4096) + loff;
      short* vd = lds + 8192 + ((kt & 1) ? 0 : 4096) + loff;
      GL2LDS(k2,                   kd);
      GL2LDS(k2 + 2048,            kd + 2048);
      GL2LDS(v2,                   vd);
      GL2LDS(v2 + (size_t)32 * S_, vd + 2048);
    }

    // S^T = K·Q^T (32x32x16, K over d=64 in 4 steps). A=K rows s=sb*32+l31, B=aq.
    f32x16 sacc[2];
    __builtin_amdgcn_s_setprio(1);
#pragma unroll
    for (int sb = 0; sb < 2; ++sb) {
      const short* kr = Kc + (sb * 32 + l31) * 64;
      short8 k0 = *(const short8*)(kr + (((0 + h5) ^ rsw) * 8));
      short8 k1 = *(const short8*)(kr + (((2 + h5) ^ rsw) * 8));
      short8 k2 = *(const short8*)(kr + (((4 + h5) ^ rsw) * 8));
      short8 k3 = *(const short8*)(kr + (((6 + h5) ^ rsw) * 8));
      f32x16 s = __builtin_amdgcn_mfma_f32_32x32x16_bf16(k0, aq[0], z16, 0, 0, 0);
      s = __builtin_amdgcn_mfma_f32_32x32x16_bf16(k1, aq[1], s, 0, 0, 0);
      s = __builtin_amdgcn_mfma_f32_32x32x16_bf16(k2, aq[2], s, 0, 0, 0);
      s = __builtin_amdgcn_mfma_f32_32x32x16_bf16(k3, aq[3], s, 0, 0, 0);
      sacc[sb] = s;
    }
    __builtin_amdgcn_s_setprio(0);

    // softmax (log2 domain, exact): e-reg r holds s_local = (r&3)+8*(r>>2)+4*h5 for q=l31.
    // Straight pack -> ap element j holds s = 16t + (j&3)+8*(j>>2)+4*h5, matching the
    // pre-permuted V exactly (same s at same (half, elem)): no cross-lane ops needed.
    short8 ap[4];
#pragma unroll
    for (int sb = 0; sb < 2; ++sb) {
      float e[16];
#pragma unroll
      for (int i = 0; i < 16; ++i) e[i] = fexp2(sacc[sb][i]);
      lsum += (((e[0] + e[1]) + (e[2] + e[3])) + ((e[4] + e[5]) + (e[6] + e[7])))
            + (((e[8] + e[9]) + (e[10] + e[11])) + ((e[12] + e[13]) + (e[14] + e[15])));
      union { unsigned u[4]; short8 s8; } lo, hi;
      lo.u[0] = pack_bf16(e[0], e[1]);   lo.u[1] = pack_bf16(e[2], e[3]);
      lo.u[2] = pack_bf16(e[4], e[5]);   lo.u[3] = pack_bf16(e[6], e[7]);
      hi.u[0] = pack_bf16(e[8], e[9]);   hi.u[1] = pack_bf16(e[10], e[11]);
      hi.u[2] = pack_bf16(e[12], e[13]); hi.u[3] = pack_bf16(e[14], e[15]);
      ap[sb * 2 + 0] = lo.s8;
      ap[sb * 2 + 1] = hi.s8;
    }

    // O += P V : A=ap (P rows q=l31), B=V (Vt rows d=db*32+l31, s pre-permuted in 16-blocks)
    __builtin_amdgcn_s_setprio(1);
#pragma unroll
    for (int db = 0; db < 2; ++db) {
      const short* vr = Vc + (db * 32 + l31) * 64;
      short8 v0 = *(const short8*)(vr + (((0 + h5) ^ rsw) * 8));
      short8 v1 = *(const short8*)(vr + (((2 + h5) ^ rsw) * 8));
      short8 v2 = *(const short8*)(vr + (((4 + h5) ^ rsw) * 8));
      short8 v3 = *(const short8*)(vr + (((6 + h5) ^ rsw) * 8));
      f32x16 o = oacc[db];
      o = __builtin_amdgcn_mfma_f32_32x32x16_bf16(ap[0], v0, o, 0, 0, 0);
      o = __builtin_amdgcn_mfma_f32_32x32x16_bf16(ap[1], v1, o, 0, 0, 0);
      o = __builtin_amdgcn_mfma_f32_32x32x16_bf16(ap[2], v2, o, 0, 0, 0);
      o = __builtin_amdgcn_mfma_f32_32x32x16_bf16(ap[3], v3, o, 0, 0, 0);
      oacc[db] = o;
    }
    __builtin_amdgcn_s_setprio(0);
  }

  // epilogue: row-sum per q=l31 split across lane halves; combine, invert, scale, store
  float lt = lsum + __shfl_xor(lsum, 32);
  float inv[16];
#pragma unroll
  for (int r = 0; r < 16; ++r)
    inv[r] = frcp(__shfl(lt, (r & 3) + 8 * (r >> 2) + 4 * h5, 64));
#pragma unroll
  for (int db = 0; db < 2; ++db) {
    const int col = h * HD_ + db * 32 + l31;
#pragma unroll
    for (int r = 0; r < 16; ++r) {
      const int m = b * S_ + qt * 128 + w * 32 + (r & 3) + 8 * (r >> 2) + 4 * h5;
      Out[(size_t)m * D_ + col] = f2bs(oacc[db][r] * inv[r]);
    }
  }
}

extern "C" void kernel_launch(void* const* d_in, const int* in_sizes, int n_in,
                              void* d_out, int out_size, void* d_ws, size_t ws_size,
                              hipStream_t stream) {
  const float* x   = (const float*)d_in[0];
  const float* y   = (const float*)d_in[1];
  const float* Wkv = (const float*)d_in[2];
  const float* bkv = (const float*)d_in[3];
  const float* Wq  = (const float*)d_in[4];
  const float* bq  = (const float*)d_in[5];
  const float* Wo  = (const float*)d_in[6];
  const float* bo  = (const float*)d_in[7];
  float* out = (float*)d_out;

  short* xb   = (short*)d_ws;
  short* yb   = xb + (4 << 20);
  short* Wkvt = yb + (4 << 20);
  short* Wqt  = Wkvt + (2 << 20);
  short* Wot  = Wqt + (1 << 20);
  short* Kb   = Wot + (1 << 20);
  short* Vtb  = Kb + (4 << 20);
  short* Qb   = Vtb + (4 << 20);
  short* AOb  = Qb + (4 << 20);

  prep_kernel<<<9216, 256, 0, stream>>>(x, y, xb, yb, Wkv, Wkvt, Wq, Wqt, Wo, Wot);
  proj_kernel<<<768, 256, 0, stream>>>(xb, Wkvt, bkv, Kb, Vtb, yb, Wqt, bq, Qb);
  attn_kernel<<<512, 256, 0, stream>>>(Qb, Kb, Vtb, AOb);
  gemm_o_kernel<<<dim3(16, 64), 256, 0, stream>>>(AOb, Wot, bo, out);
}

// Round 6
// 192.828 us; speedup vs baseline: 1.0746x; 1.0746x over previous
//
#include <hip/hip_runtime.h>
#include <hip/hip_bf16.h>

typedef __attribute__((ext_vector_type(8))) short short8;
typedef __attribute__((ext_vector_type(4))) short short4v;
typedef __attribute__((ext_vector_type(4))) float f32x4;
typedef __attribute__((ext_vector_type(16))) float f32x16;

#define B_  2
#define S_  2048
#define H_  16
#define HD_ 64
#define D_  1024
#define QSCALE 0.18033688f   /* 0.125 * log2(e): folds softmax exp2 conversion into Q proj */

__device__ __forceinline__ short f2bs(float f) {
  union { float f; unsigned u; } c; c.f = f;
  unsigned u = c.u;
  u += 0x7fffu + ((u >> 16) & 1u);   // RNE; inputs are never NaN
  return (short)(u >> 16);
}

__device__ __forceinline__ unsigned pack_bf16(float a, float b) {
  __hip_bfloat162 h = __float22bfloat162_rn(float2{a, b});   // v_cvt_pk_bf16_f32
  return *reinterpret_cast<unsigned*>(&h);
}

__device__ __forceinline__ float fexp2(float x) {
#if __has_builtin(__builtin_amdgcn_exp2f)
  return __builtin_amdgcn_exp2f(x);
#else
  return exp2f(x);
#endif
}

__device__ __forceinline__ float frcp(float x) {
#if __has_builtin(__builtin_amdgcn_rcpf)
  return __builtin_amdgcn_rcpf(x);
#else
  return 1.0f / x;
#endif
}

#define GL2LDS(gp, lp) __builtin_amdgcn_global_load_lds( \
    (const __attribute__((address_space(1))) unsigned int*)(gp), \
    (__attribute__((address_space(3))) unsigned int*)(lp), 16, 0, 0)

// counted-vmcnt pipeline primitives (T3/T4): raw barrier, never drain to 0 in-loop.
#define WAITCNT4  asm volatile("s_waitcnt vmcnt(4)" ::: "memory")
#define WAITCNT8  asm volatile("s_waitcnt vmcnt(8)" ::: "memory")
#define WAITCNT0  asm volatile("s_waitcnt vmcnt(0)" ::: "memory")
#define BARRIER_PIN do { __builtin_amdgcn_s_barrier(); __builtin_amdgcn_sched_barrier(0); } while (0)

// ---------------- fused prep: x/y convert + all three weight transposes ----------------
__global__ __launch_bounds__(256)
void prep_kernel(const float* __restrict__ x, const float* __restrict__ y,
                 short* __restrict__ xb, short* __restrict__ yb,
                 const float* __restrict__ Wkv, short* __restrict__ Wkvt,
                 const float* __restrict__ Wq, short* __restrict__ Wqt,
                 const float* __restrict__ Wo, short* __restrict__ Wot) {
  __shared__ float tile[64][65];
  int bx = blockIdx.x;
  if (bx < 8192) {                      // convert x (1M float4) then y (1M float4)
    int i = bx * 256 + threadIdx.x;
    const float4* src; short4v* dst; int j;
    if (i < (1 << 20)) { src = (const float4*)x; dst = (short4v*)xb; j = i; }
    else               { src = (const float4*)y; dst = (short4v*)yb; j = i - (1 << 20); }
    float4 f = src[j];
    short4v o;
    o.x = f2bs(f.x); o.y = f2bs(f.y); o.z = f2bs(f.z); o.w = f2bs(f.w);
    dst[j] = o;
    return;
  }
  bx -= 8192;
  const float* in; short* out; int C, c0, r0;
  if (bx < 512)      { in = Wkv; out = Wkvt; C = 2048; c0 = (bx & 31) * 64; r0 = (bx >> 5) * 64; }
  else if (bx < 768) { bx -= 512; in = Wq; out = Wqt; C = 1024; c0 = (bx & 15) * 64; r0 = (bx >> 4) * 64; }
  else               { bx -= 768; in = Wo; out = Wot; C = 1024; c0 = (bx & 15) * 64; r0 = (bx >> 4) * 64; }
  const int tx = threadIdx.x & 63, ty = threadIdx.x >> 6;
#pragma unroll
  for (int i = 0; i < 16; ++i) {
    int r = ty + i * 4;
    tile[r][tx] = in[(size_t)(r0 + r) * C + c0 + tx];
  }
  __syncthreads();
#pragma unroll
  for (int i = 0; i < 16; ++i) {
    int r = ty + i * 4;
    out[(size_t)(c0 + r) * 1024 + r0 + tx] = f2bs(tile[tx][r]);
  }
}

// ---------------- GEMM body: C[128,128] tile of A[M,K] @ Bt[N,K]^T + bias ----------------
// 3-deep LDS pipeline (As[3]|Bs[3], 8KB each), BK=32, prefetch 2 tiles ahead, ONE raw
// barrier + counted s_waitcnt vmcnt(4) per K-step (never drains in-loop) -> DMA latency
// spans a full iteration (T3/T4).
// MODE 1's Vt output is stored with the s-dim PERMUTED within 16-blocks (dword order
// [0,1,4,5,2,3,6,7] per 8-dword block) so attn's PV A-fragment is the straight pack of
// each lane's own softmax registers (no cross-lane redistribution needed).
template <int MODE>
__device__ __forceinline__ void gemm_body(const short* __restrict__ A, const short* __restrict__ Bt,
                                          const float* __restrict__ bias,
                                          void* __restrict__ out0, void* __restrict__ out1,
                                          int m0, int n0, int K, short* smem) {
  short* As_ = smem;            // 3 x 4096 shorts
  short* Bs_ = smem + 12288;    // 3 x 4096 shorts
  const int tid = threadIdx.x;
  const int w = tid >> 6, lane = tid & 63;
  const int q15 = lane & 15, quad = lane >> 4;
  const int wm = (w >> 1) * 64, wn = (w & 1) * 64;

  f32x4 acc[4][4];
#pragma unroll
  for (int i = 0; i < 4; ++i)
#pragma unroll
    for (int j = 0; j < 4; ++j) acc[i][j] = f32x4{0.f, 0.f, 0.f, 0.f};

  const int srow = w * 16 + (lane >> 2);                    // row 0..63 (first half)
  const int gch  = (lane & 3) ^ ((lane >> 3) & 3);          // swizzled global chunk
  const short* Ag = A + (size_t)(m0 + srow) * K + gch * 8;
  const short* Bg = Bt + (size_t)(n0 + srow) * K + gch * 8;
  const int lof = srow * 32 + (lane & 3) * 8;

#define STAGE_AB(t, buf) do { \
    const short* a2 = Ag + (size_t)(t) * 32; \
    const short* b2 = Bg + (size_t)(t) * 32; \
    short* ad = As_ + (buf) * 4096 + lof; \
    short* bd = Bs_ + (buf) * 4096 + lof; \
    GL2LDS(a2,                  ad); \
    GL2LDS(a2 + (size_t)64 * K, ad + 2048); \
    GL2LDS(b2,                  bd); \
    GL2LDS(b2 + (size_t)64 * K, bd + 2048); \
  } while (0)

  const int NT = K >> 5;
  STAGE_AB(0, 0);
  STAGE_AB(1, 1);
  int cb = 0, ib = 2;
  for (int kt = 0; kt < NT; ++kt) {
    if (kt < NT - 1) WAITCNT4; else WAITCNT0;   // tile kt's 4 DMAs done (issued 2 iters ago)
    BARRIER_PIN;                                 // all waves agree; no full drain
    if (kt + 2 < NT) STAGE_AB(kt + 2, ib);       // issue-ahead into the freed buffer
    const short* Ac = As_ + cb * 4096;
    const short* Bc = Bs_ + cb * 4096;
    short8 af[4], bf[4];
#pragma unroll
    for (int mi = 0; mi < 4; ++mi) {
      int rr = wm + mi * 16 + q15;
      af[mi] = *(const short8*)(Ac + rr * 32 + ((quad ^ ((rr >> 1) & 3)) * 8));
    }
#pragma unroll
    for (int ni = 0; ni < 4; ++ni) {
      int rr = wn + ni * 16 + q15;
      bf[ni] = *(const short8*)(Bc + rr * 32 + ((quad ^ ((rr >> 1) & 3)) * 8));
    }
#pragma unroll
    for (int mi = 0; mi < 4; ++mi)
#pragma unroll
      for (int ni = 0; ni < 4; ++ni)
        acc[mi][ni] = __builtin_amdgcn_mfma_f32_16x16x32_bf16(af[mi], bf[ni], acc[mi][ni], 0, 0, 0);
    cb = (cb == 2) ? 0 : cb + 1;
    ib = (ib == 2) ? 0 : ib + 1;
  }
#undef STAGE_AB
  __syncthreads();                        // protect smem (VT transpose region) reuse below

  if constexpr (MODE == 0) {
#pragma unroll
    for (int mi = 0; mi < 4; ++mi)
#pragma unroll
      for (int ni = 0; ni < 4; ++ni) {
        const int n = n0 + wn + ni * 16 + q15;
        const float bn = bias[n];
#pragma unroll
        for (int r = 0; r < 4; ++r) {
          const int m = m0 + wm + mi * 16 + quad * 4 + r;
          int b = m >> 11, s = m & 2047, hh = n >> 6, d = n & 63;
          ((short*)out0)[((size_t)((b * H_ + hh) * S_ + s) << 6) + d] = f2bs((acc[mi][ni][r] + bn) * QSCALE);
        }
      }
  } else {
    const int hh = n0 >> 7;
    const int bb = m0 >> 11;
    const size_t bh = (size_t)(bb * H_ + hh);
    const int s0 = m0 & 2047;
    if ((w & 1) == 0) {
#pragma unroll
      for (int mi = 0; mi < 4; ++mi)
#pragma unroll
        for (int ni = 0; ni < 4; ++ni) {
          const float bn = bias[n0 + ni * 16 + q15];
#pragma unroll
          for (int r = 0; r < 4; ++r) {
            const int s = s0 + wm + mi * 16 + quad * 4 + r;
            ((short*)out0)[((bh * S_ + s) << 6) + ni * 16 + q15] = f2bs(acc[mi][ni][r] + bn);
          }
        }
    } else {
      short* VT = smem;
#pragma unroll
      for (int mi = 0; mi < 4; ++mi)
#pragma unroll
        for (int ni = 0; ni < 4; ++ni) {
          const int d = ni * 16 + q15;
          const float bn = bias[n0 + 64 + ni * 16 + q15];
#pragma unroll
          for (int t = 0; t < 2; ++t) {
            const int chunk = (wm >> 1) + mi * 8 + quad * 2 + t;
            unsigned pk = pack_bf16(acc[mi][ni][2 * t] + bn, acc[mi][ni][2 * t + 1] + bn);
            *reinterpret_cast<unsigned*>(VT + d * 128 + ((chunk ^ (d & 15)) * 2)) = pk;
          }
        }
    }
    __syncthreads();
    {
      short* VT = smem;
      const int d = tid >> 2, t4 = tid & 3;
      unsigned vals[16];
#pragma unroll
      for (int c = 0; c < 16; ++c) {
        int chunk = t4 * 16 + c;
        vals[c] = *reinterpret_cast<unsigned*>(VT + d * 128 + ((chunk ^ (d & 15)) * 2));
      }
      uint4* dst = (uint4*)((short*)out1 + ((bh * HD_ + d) << 11) + s0 + t4 * 32);
      // s-permuted store: per 8-dword block, stored order [0,1,4,5,2,3,6,7] so that
      // stored position 16t+8h+j holds s = 16t + (j&3) + 8*(j>>2) + 4h (attn PV pairing).
      dst[0] = uint4{vals[0], vals[1], vals[4],  vals[5]};
      dst[1] = uint4{vals[2], vals[3], vals[6],  vals[7]};
      dst[2] = uint4{vals[8], vals[9], vals[12], vals[13]};
      dst[3] = uint4{vals[10], vals[11], vals[14], vals[15]};
    }
  }
}

// fused stage-1: logical blocks [0,512) -> KV proj, [512,768) -> Q proj.
// XCD-chunked remap (768 % 8 == 0, bijective).
__global__ __launch_bounds__(256)
void proj_kernel(const short* __restrict__ xb, const short* __restrict__ Wkvt,
                 const float* __restrict__ bkv, short* __restrict__ Kb, short* __restrict__ Vtb,
                 const short* __restrict__ yb, const short* __restrict__ Wqt,
                 const float* __restrict__ bq, short* __restrict__ Qb) {
  __shared__ __align__(16) short smem[24576];   // As[3]|Bs[3], 48 KB -> 3 blocks/CU
  int bx = blockIdx.x;
  bx = (bx & 7) * 96 + (bx >> 3);
  if (bx < 512)
    gemm_body<1>(xb, Wkvt, bkv, Kb, Vtb, (bx >> 4) * 128, (bx & 15) * 128, 1024, smem);
  else {
    bx -= 512;
    gemm_body<0>(yb, Wqt, bq, Qb, nullptr, (bx >> 3) * 128, (bx & 7) * 128, 1024, smem);
  }
}

// ---------------- O projection: 64x64 tile, BK=64, double-buffered, 1 barrier/iter ----------------
__global__ __launch_bounds__(256)
void gemm_o_kernel(const short* __restrict__ A, const short* __restrict__ Bt,
                   const float* __restrict__ bias, float* __restrict__ out) {
  __shared__ __align__(16) short lds[16384];    // A0|A1|B0|B1, 4096 shorts each
  const int tid = threadIdx.x;
  const int w = tid >> 6, lane = tid & 63;
  const int q15 = lane & 15, quad = lane >> 4;
  const int m0 = blockIdx.y * 64, n0 = blockIdx.x * 64;
  const int wm = (w >> 1) * 32, wn = (w & 1) * 32;
  const int xw = q15 & 7;

  f32x4 acc[2][2];
#pragma unroll
  for (int i = 0; i < 2; ++i)
#pragma unroll
    for (int j = 0; j < 2; ++j) acc[i][j] = f32x4{0.f, 0.f, 0.f, 0.f};

  const int srow = w * 8 + (lane >> 3);          // 0..31
  const int gch  = (lane & 7) ^ (srow & 7);
  const int loff = w * 512 + lane * 8;
  const short* Ag = A + (size_t)(m0 + srow) * 1024 + gch * 8;
  const short* Bg = Bt + (size_t)(n0 + srow) * 1024 + gch * 8;

  GL2LDS(Ag,             lds + loff);
  GL2LDS(Ag + 32 * 1024, lds + loff + 2048);
  GL2LDS(Bg,             lds + 8192 + loff);
  GL2LDS(Bg + 32 * 1024, lds + 8192 + loff + 2048);

  for (int kt = 0; kt < 16; ++kt) {
    __syncthreads();                            // cur buf DMA done; prev reads drained
    const short* Ac = lds + ((kt & 1) ? 4096 : 0);
    const short* Bc = lds + 8192 + ((kt & 1) ? 4096 : 0);
    if (kt < 15) {
      const short* a2 = Ag + (kt + 1) * 64;
      const short* b2 = Bg + (kt + 1) * 64;
      short* ad = lds + ((kt & 1) ? 0 : 4096) + loff;
      short* bd = lds + 8192 + ((kt & 1) ? 0 : 4096) + loff;
      GL2LDS(a2,             ad);
      GL2LDS(a2 + 32 * 1024, ad + 2048);
      GL2LDS(b2,             bd);
      GL2LDS(b2 + 32 * 1024, bd + 2048);
    }
    short8 af[2][2], bf[2][2];
#pragma unroll
    for (int mi = 0; mi < 2; ++mi)
#pragma unroll
      for (int kk = 0; kk < 2; ++kk)
        af[mi][kk] = *(const short8*)(Ac + (wm + mi * 16 + q15) * 64 + (((kk * 4 + quad) ^ xw) * 8));
#pragma unroll
    for (int ni = 0; ni < 2; ++ni)
#pragma unroll
      for (int kk = 0; kk < 2; ++kk)
        bf[ni][kk] = *(const short8*)(Bc + (wn + ni * 16 + q15) * 64 + (((kk * 4 + quad) ^ xw) * 8));
#pragma unroll
    for (int mi = 0; mi < 2; ++mi)
#pragma unroll
      for (int ni = 0; ni < 2; ++ni)
#pragma unroll
        for (int kk = 0; kk < 2; ++kk)
          acc[mi][ni] = __builtin_amdgcn_mfma_f32_16x16x32_bf16(af[mi][kk], bf[ni][kk], acc[mi][ni], 0, 0, 0);
  }

#pragma unroll
  for (int mi = 0; mi < 2; ++mi)
#pragma unroll
    for (int ni = 0; ni < 2; ++ni) {
      const int n = n0 + wn + ni * 16 + q15;
      const float bn = bias[n];
#pragma unroll
      for (int r = 0; r < 4; ++r) {
        const int m = m0 + wm + mi * 16 + quad * 4 + r;
        out[(size_t)m * 1024 + n] = acc[mi][ni][r] + bn;
      }
    }
}

// ---------------- flash attention: 32x32x16 MFMA, in-register P, counted-vmcnt pipeline ----
// grid 512 (XCD-swizzled: 4 (b,h) pairs per XCD x 16 q-tiles). 256 threads = 4 waves; q-tile
// 128 rows; wave owns 32 q-rows (q = lane&31). 3-deep K/V LDS buffers, prefetch 2 tiles
// ahead, one raw barrier + s_waitcnt vmcnt(4) per iter (T3/T4) -> DMA spans a full iter.
// Swapped QK^T; softmax lane-local; PV A-fragment = straight pack of own exp values against
// the proj-time s-permuted V (verified round 4). No P LDS.
// Q pre-scaled by 0.125*log2e (scores in log2 domain, no-max exact softmax).
// LDS (shorts): Ks[3][4096] @0 | Vs[3][4096] @12288 | Q[8192] @24576 = 64 KB, 2 blocks/CU.
__global__ __launch_bounds__(256, 2)
void attn_kernel(const short* __restrict__ Q, const short* __restrict__ K,
                 const short* __restrict__ Vt, short* __restrict__ Out) {
  __shared__ __align__(16) short lds[32768];
  short* QP = lds + 24576;
  const int tid = threadIdx.x;
  const int w = tid >> 6, lane = tid & 63;     // w in 0..3
  const int l31 = lane & 31, h5 = lane >> 5;
  const int rsw = l31 & 7;                     // row-XOR swizzle (rows == l31 mod 8 everywhere)
  const int bx = blockIdx.x;
  const int xcd = bx & 7, slot = bx >> 3;      // slot 0..63
  const int pp = xcd * 4 + (slot >> 4);        // (b,h) pair: 4 per XCD
  const int qt = slot & 15;                    // 16 q-tiles of 128 rows
  const int h = pp & 15, b = pp >> 4;
  const size_t bh = (size_t)(b * H_ + h);
  const short* Qg = Q + bh * (S_ * HD_) + qt * (128 * HD_);
  const short* Kg = K + bh * (S_ * HD_);
  const short* Vg = Vt + bh * (HD_ * S_);

  const int srow = tid >> 3;                   // 0..31
  const int gch  = (tid & 7) ^ (srow & 7);
  const int loff = tid * 8;                    // shorts, 0..2047

  const short* kg = Kg + srow * 64 + gch * 8;
  const short* vg = Vg + (size_t)srow * S_ + gch * 8;

#define STAGE_KV(t, buf) do { \
    const short* k2 = kg + (size_t)(t) * 4096; \
    const short* v2 = vg + (size_t)(t) * 64; \
    short* kd = lds + (buf) * 4096 + loff; \
    short* vd = lds + 12288 + (buf) * 4096 + loff; \
    GL2LDS(k2,                   kd); \
    GL2LDS(k2 + 2048,            kd + 2048); \
    GL2LDS(v2,                   vd); \
    GL2LDS(v2 + (size_t)32 * S_, vd + 2048); \
  } while (0)

  // prologue: Q (4 DMAs) then K/V tiles 0,1 (4 DMAs each) = 12 outstanding
  {
    const short* qg = Qg + srow * 64 + gch * 8;
#pragma unroll
    for (int t = 0; t < 4; ++t) GL2LDS(qg + t * 2048, QP + loff + t * 2048);
  }
  STAGE_KV(0, 0);
  STAGE_KV(1, 1);
  WAITCNT8;                                    // Q's 4 (oldest) complete; K/V stay in flight
  BARRIER_PIN;

  // Q B-fragment: col q = l31 (tile row w*32+l31), k = d = kk*16 + h5*8 + j
  short8 aq[4];
#pragma unroll
  for (int kk = 0; kk < 4; ++kk)
    aq[kk] = *(const short8*)(QP + (w * 32 + l31) * 64 + (((kk * 2 + h5) ^ rsw) * 8));

  f32x16 oacc[2];
#pragma unroll
  for (int i = 0; i < 16; ++i) { oacc[0][i] = 0.f; oacc[1][i] = 0.f; }
  float lsum = 0.f;
  f32x16 z16;
#pragma unroll
  for (int i = 0; i < 16; ++i) z16[i] = 0.f;

  int cb = 0, ib = 2;
  for (int kt = 0; kt < 32; ++kt) {
    if (kt < 31) WAITCNT4; else WAITCNT0;      // tile kt's 4 DMAs done (issued 2 iters ago)
    BARRIER_PIN;
    if (kt + 2 < 32) STAGE_KV(kt + 2, ib);     // issue-ahead into the freed buffer
    const short* Kc = lds + cb * 4096;
    const short* Vc = lds + 12288 + cb * 4096;

    // S^T = K·Q^T (32x32x16, K over d=64 in 4 steps). A=K rows s=sb*32+l31, B=aq.
    f32x16 sacc[2];
    __builtin_amdgcn_s_setprio(1);
#pragma unroll
    for (int sb = 0; sb < 2; ++sb) {
      const short* kr = Kc + (sb * 32 + l31) * 64;
      short8 k0 = *(const short8*)(kr + (((0 + h5) ^ rsw) * 8));
      short8 k1 = *(const short8*)(kr + (((2 + h5) ^ rsw) * 8));
      short8 k2 = *(const short8*)(kr + (((4 + h5) ^ rsw) * 8));
      short8 k3 = *(const short8*)(kr + (((6 + h5) ^ rsw) * 8));
      f32x16 s = __builtin_amdgcn_mfma_f32_32x32x16_bf16(k0, aq[0], z16, 0, 0, 0);
      s = __builtin_amdgcn_mfma_f32_32x32x16_bf16(k1, aq[1], s, 0, 0, 0);
      s = __builtin_amdgcn_mfma_f32_32x32x16_bf16(k2, aq[2], s, 0, 0, 0);
      s = __builtin_amdgcn_mfma_f32_32x32x16_bf16(k3, aq[3], s, 0, 0, 0);
      sacc[sb] = s;
    }
    __builtin_amdgcn_s_setprio(0);

    // softmax (log2 domain, exact): e-reg r holds s_local = (r&3)+8*(r>>2)+4*h5 for q=l31.
    // Straight pack -> ap element j holds s = 16t + (j&3)+8*(j>>2)+4*h5, matching the
    // pre-permuted V exactly (same s at same (half, elem)): no cross-lane ops needed.
    short8 ap[4];
#pragma unroll
    for (int sb = 0; sb < 2; ++sb) {
      float e[16];
#pragma unroll
      for (int i = 0; i < 16; ++i) e[i] = fexp2(sacc[sb][i]);
      lsum += (((e[0] + e[1]) + (e[2] + e[3])) + ((e[4] + e[5]) + (e[6] + e[7])))
            + (((e[8] + e[9]) + (e[10] + e[11])) + ((e[12] + e[13]) + (e[14] + e[15])));
      union { unsigned u[4]; short8 s8; } lo, hi;
      lo.u[0] = pack_bf16(e[0], e[1]);   lo.u[1] = pack_bf16(e[2], e[3]);
      lo.u[2] = pack_bf16(e[4], e[5]);   lo.u[3] = pack_bf16(e[6], e[7]);
      hi.u[0] = pack_bf16(e[8], e[9]);   hi.u[1] = pack_bf16(e[10], e[11]);
      hi.u[2] = pack_bf16(e[12], e[13]); hi.u[3] = pack_bf16(e[14], e[15]);
      ap[sb * 2 + 0] = lo.s8;
      ap[sb * 2 + 1] = hi.s8;
    }

    // O += P V : A=ap (P rows q=l31), B=V (Vt rows d=db*32+l31, s pre-permuted in 16-blocks)
    __builtin_amdgcn_s_setprio(1);
#pragma unroll
    for (int db = 0; db < 2; ++db) {
      const short* vr = Vc + (db * 32 + l31) * 64;
      short8 v0 = *(const short8*)(vr + (((0 + h5) ^ rsw) * 8));
      short8 v1 = *(const short8*)(vr + (((2 + h5) ^ rsw) * 8));
      short8 v2 = *(const short8*)(vr + (((4 + h5) ^ rsw) * 8));
      short8 v3 = *(const short8*)(vr + (((6 + h5) ^ rsw) * 8));
      f32x16 o = oacc[db];
      o = __builtin_amdgcn_mfma_f32_32x32x16_bf16(ap[0], v0, o, 0, 0, 0);
      o = __builtin_amdgcn_mfma_f32_32x32x16_bf16(ap[1], v1, o, 0, 0, 0);
      o = __builtin_amdgcn_mfma_f32_32x32x16_bf16(ap[2], v2, o, 0, 0, 0);
      o = __builtin_amdgcn_mfma_f32_32x32x16_bf16(ap[3], v3, o, 0, 0, 0);
      oacc[db] = o;
    }
    __builtin_amdgcn_s_setprio(0);
    cb = (cb == 2) ? 0 : cb + 1;
    ib = (ib == 2) ? 0 : ib + 1;
  }
#undef STAGE_KV

  // epilogue: row-sum per q=l31 split across lane halves; combine, invert, scale, store
  float lt = lsum + __shfl_xor(lsum, 32);
  float inv[16];
#pragma unroll
  for (int r = 0; r < 16; ++r)
    inv[r] = frcp(__shfl(lt, (r & 3) + 8 * (r >> 2) + 4 * h5, 64));
#pragma unroll
  for (int db = 0; db < 2; ++db) {
    const int col = h * HD_ + db * 32 + l31;
#pragma unroll
    for (int r = 0; r < 16; ++r) {
      const int m = b * S_ + qt * 128 + w * 32 + (r & 3) + 8 * (r >> 2) + 4 * h5;
      Out[(size_t)m * D_ + col] = f2bs(oacc[db][r] * inv[r]);
    }
  }
}

extern "C" void kernel_launch(void* const* d_in, const int* in_sizes, int n_in,
                              void* d_out, int out_size, void* d_ws, size_t ws_size,
                              hipStream_t stream) {
  const float* x   = (const float*)d_in[0];
  const float* y   = (const float*)d_in[1];
  const float* Wkv = (const float*)d_in[2];
  const float* bkv = (const float*)d_in[3];
  const float* Wq  = (const float*)d_in[4];
  const float* bq  = (const float*)d_in[5];
  const float* Wo  = (const float*)d_in[6];
  const float* bo  = (const float*)d_in[7];
  float* out = (float*)d_out;

  short* xb   = (short*)d_ws;
  short* yb   = xb + (4 << 20);
  short* Wkvt = yb + (4 << 20);
  short* Wqt  = Wkvt + (2 << 20);
  short* Wot  = Wqt + (1 << 20);
  short* Kb   = Wot + (1 << 20);
  short* Vtb  = Kb + (4 << 20);
  short* Qb   = Vtb + (4 << 20);
  short* AOb  = Qb + (4 << 20);

  prep_kernel<<<9216, 256, 0, stream>>>(x, y, xb, yb, Wkv, Wkvt, Wq, Wqt, Wo, Wot);
  proj_kernel<<<768, 256, 0, stream>>>(xb, Wkvt, bkv, Kb, Vtb, yb, Wqt, bq, Qb);
  attn_kernel<<<512, 256, 0, stream>>>(Qb, Kb, Vtb, AOb);
  gemm_o_kernel<<<dim3(16, 64), 256, 0, stream>>>(AOb, Wot, bo, out);
}